// Round 4
// baseline (62.832 us; speedup 1.0000x reference)
//
#include <hip/hip_runtime.h>

// out[i, 7n+o, m] = sum_{j,k} x[j, 7n+o+k-1, m] * W[i,j,k], taps clipped to o+k-1 in [0,7)
// x: (48,56,56) f32, W: (192,48,3) f32, out: (192,56,56) f32
//
// R4: split-j(16). Block = 256 thr = 16 columns x 16 j-segments (JSEG=3).
// Grid = 192 i * 7 colgroups = 1344 blocks -> 5376 waves (21/CU).
// i is blockIdx-derived (scalar W addressing). LDS reduce 16 segments.

#define CH_IN 48
#define CH_OUT 192
#define HW 56
#define SP 3136   // 56*56
#define OB 7      // rows per n-block
#define M4 14     // float4 chunks per 56-wide row
#define COLS 112  // spatial columns per channel (8 n-blocks * 14 m4)
#define SEGS 16
#define JSEG (CH_IN / SEGS)   // 3
#define BCOL 16               // columns per block
#define CG 7                  // colgroups per channel (112/16)

__device__ __forceinline__ void fma4(float4& a, float s, const float4& b) {
    a.x += s * b.x; a.y += s * b.y; a.z += s * b.z; a.w += s * b.w;
}
__device__ __forceinline__ void add4(float4& a, const float4& b) {
    a.x += b.x; a.y += b.y; a.z += b.z; a.w += b.w;
}

__global__ __launch_bounds__(256) void conv_split16_kernel(const float* __restrict__ x,
                                                           const float* __restrict__ W,
                                                           float* __restrict__ out) {
    __shared__ float4 lds[SEGS][OB][BCOL];   // 28 KB

    const int c   = threadIdx.x & (BCOL - 1);   // column within block
    const int seg = threadIdx.x >> 4;           // j-segment [0,16)
    const int i   = blockIdx.x / CG;            // output channel (blockIdx-only -> scalar)
    const int cg  = blockIdx.x % CG;

    const int col = cg * BCOL + c;              // [0,112)
    const int n   = col / M4;
    const int m4  = col % M4;

    const float* xcol = x + seg * (JSEG * SP) + n * (OB * HW) + m4 * 4;
    const float* wrow = W + i * (CH_IN * 3) + seg * (JSEG * 3);

    float4 acc[OB];
#pragma unroll
    for (int o = 0; o < OB; ++o) acc[o] = make_float4(0.f, 0.f, 0.f, 0.f);

#pragma unroll
    for (int j = 0; j < JSEG; ++j) {
        const float w0 = wrow[j * 3 + 0];
        const float w1 = wrow[j * 3 + 1];
        const float w2 = wrow[j * 3 + 2];

        const float* xj = xcol + j * SP;
        float4 xv[OB];
#pragma unroll
        for (int o = 0; o < OB; ++o)
            xv[o] = *reinterpret_cast<const float4*>(xj + o * HW);

#pragma unroll
        for (int o = 0; o < OB; ++o) {
            if (o > 0)      fma4(acc[o], w0, xv[o - 1]);  // k=0 tap
            fma4(acc[o], w1, xv[o]);                      // k=1 tap
            if (o < OB - 1) fma4(acc[o], w2, xv[o + 1]);  // k=2 tap
        }
    }

#pragma unroll
    for (int o = 0; o < OB; ++o) lds[seg][o][c] = acc[o];
    __syncthreads();

    // 112 outputs (7 rows x 16 cols) per block; threads 0..111 fold 16 segments.
    const int t = threadIdx.x;
    if (t < OB * BCOL) {
        const int o  = t >> 4;
        const int cc = t & (BCOL - 1);
        float4 s = lds[0][o][cc];
#pragma unroll
        for (int sgi = 1; sgi < SEGS; ++sgi) add4(s, lds[sgi][o][cc]);

        const int col2 = cg * BCOL + cc;
        const int n2   = col2 / M4;
        const int m42  = col2 % M4;
        *reinterpret_cast<float4*>(out + i * SP + n2 * (OB * HW) + o * HW + m42 * 4) = s;
    }
}

extern "C" void kernel_launch(void* const* d_in, const int* in_sizes, int n_in,
                              void* d_out, int out_size, void* d_ws, size_t ws_size,
                              hipStream_t stream) {
    const float* x = (const float*)d_in[0];
    const float* W = (const float*)d_in[1];
    float* out = (float*)d_out;

    const int grid = CH_OUT * CG;  // 1344 blocks x 256 threads
    conv_split16_kernel<<<grid, 256, 0, stream>>>(x, W, out);
}